// Round 3
// baseline (211.832 us; speedup 1.0000x reference)
//
#include <hip/hip_runtime.h>
#include <hip/hip_bf16.h>
#include <hip/hip_fp16.h>

// Fused AdvancedHomeostaticCell, round 3 (= round-2 design, compile fix:
// __exp2f -> __builtin_amdgcn_exp2f).
// Two-pass GEMM1 (i,s then f) + per-T GEMM2 epilogue to cut peak live
// registers; packed f32->bf16/f16 converts via HW cvt_pk; rcp/exp2 fast
// intrinsics. Zero LDS, zero barriers, operand-swapped MFMA.

typedef __attribute__((ext_vector_type(8)))  short short8;
typedef __attribute__((ext_vector_type(16))) float f32x16;

__device__ __forceinline__ unsigned short f2bf(float f) {   // prep kernels only
    union { float f; unsigned u; } v; v.f = f;
    unsigned r = v.u + 0x7fffu + ((v.u >> 16) & 1u);
    return (unsigned short)(r >> 16);
}
__device__ __forceinline__ float bf2f(unsigned hs) {
    union { unsigned u; float f; } v; v.u = hs << 16;
    return v.f;
}
__device__ __forceinline__ unsigned pk_bf16(float lo, float hi) {
    union { __hip_bfloat162 h; unsigned u; } c;
    c.h = __float22bfloat162_rn(make_float2(lo, hi));
    return c.u;
}
__device__ __forceinline__ unsigned pk_f16(float lo, float hi) {
    union { __half2 h; unsigned u; } c;
    c.h = __floats2half2_rn(lo, hi);
    return c.u;
}
__device__ __forceinline__ float lo_f16(unsigned u) {
    union { unsigned u; __half2 h; } c; c.u = u;
    return __low2float(c.h);
}
__device__ __forceinline__ float hi_f16(unsigned u) {
    union { unsigned u; __half2 h; } c; c.u = u;
    return __high2float(c.h);
}
__device__ __forceinline__ float rcp_fast(float x) { return __builtin_amdgcn_rcpf(x); }
__device__ __forceinline__ float exp2_fast(float x) { return __builtin_amdgcn_exp2f(x); }
__device__ __forceinline__ float sigm(float x) {
    return rcp_fast(1.0f + exp2_fast(-1.4426950408889634f * x));
}
__device__ __forceinline__ float tanh_fast(float x) {
    return 1.0f - 2.0f * rcp_fast(1.0f + exp2_fast(2.8853900817779268f * x));
}
__device__ __forceinline__ f32x16 mfma_bf16(short8 a, short8 b, f32x16 c) {
    return __builtin_amdgcn_mfma_f32_32x32x16_bf16(a, b, c, 0, 0, 0);
}

// ---------- prep: cast weights to bf16 (Wcat = [Wi; Wf_x; Wslow+Wfast]) ----
__global__ void prep_weights(const float* __restrict__ Wi_w,
                             const float* __restrict__ Wf_w,
                             const float* __restrict__ Ws_w,
                             const float* __restrict__ Wfast_w,
                             const float* __restrict__ Wo_w,
                             unsigned short* __restrict__ Wcat,
                             unsigned short* __restrict__ Wo) {
    int gid = blockIdx.x * 256 + threadIdx.x;           // 0 .. 65535
    if (gid < 384 * 128) {
        int n = gid >> 7, k = gid & 127;
        float v;
        if (n < 128)      v = Wi_w[n * 128 + k];
        else if (n < 256) v = Wf_w[(n - 128) * 256 + k];          // x-half of Wf
        else              v = Ws_w[(n - 256) * 128 + k] + Wfast_w[(n - 256) * 128 + k];
        Wcat[gid] = f2bf(v);
    } else {
        int i = gid - 384 * 128;                        // < 16384
        Wo[i] = f2bf(Wo_w[i]);
    }
}

// fbias[j] = Wf_b[j] + sum_k Wf_w[j][128+k] * h_prev[k]
__global__ void prep_fbias(const float* __restrict__ Wf_w,
                           const float* __restrict__ Wf_b,
                           const float* __restrict__ hp,
                           float* __restrict__ fbias) {
    int j = threadIdx.x;
    float s = Wf_b[j];
    for (int k = 0; k < 128; ++k) s += Wf_w[j * 256 + 128 + k] * hp[k];
    fbias[j] = s;
}

// ------------------------------ main fused kernel --------------------------
__global__ __launch_bounds__(256, 3)
void cell_main(const float* __restrict__ x,
               const float* __restrict__ hp,
               const float* __restrict__ Wi_b,
               const float* __restrict__ Ws_b,
               const float* __restrict__ Wo_b,
               const float* __restrict__ ln_g,
               const float* __restrict__ ln_b,
               const unsigned short* __restrict__ Wcat,
               const unsigned short* __restrict__ Wo,
               const float* __restrict__ fbias,
               float* __restrict__ out) {
    const int tid  = threadIdx.x;
    const int lane = tid & 63;
    const int warp = tid >> 6;
    const int lm   = lane & 31;          // column m within wave tile / weight row
    const int h    = lane >> 5;          // half-wave selector (k-block)
    const int wave_id = blockIdx.x * 4 + warp;
    const int m = wave_id * 32 + lm;     // this lane's batch row

    // --- preload this row's x as 8 bf16 B-fragments (k = 16*ks + 8*h + 0..7) ---
    short8 xf[8];
    const float* xrow = x + (size_t)m * 128 + h * 8;
    #pragma unroll
    for (int ks = 0; ks < 8; ++ks) {
        const float4 a = *(const float4*)(xrow + ks * 16);
        const float4 b = *(const float4*)(xrow + ks * 16 + 4);
        union { unsigned u[4]; short8 s8; } v;
        v.u[0] = pk_bf16(a.x, a.y); v.u[1] = pk_bf16(a.z, a.w);
        v.u[2] = pk_bf16(b.x, b.y); v.u[3] = pk_bf16(b.z, b.w);
        xf[ks] = v.s8;
    }

    // ---------------- GEMM1 pass 1: i and s gates -> part = sigm(i)*(s+b) ----
    // acc layout (32x32x16): col = lane&31 (=m), row = (r&3)+8*(r>>2)+4*h
    unsigned ppk[32];                    // part packed f16 pairs
    #pragma unroll
    for (int jg = 0; jg < 4; ++jg) {
        f32x16 acc_i, acc_s;
        #pragma unroll
        for (int e = 0; e < 16; ++e) { acc_i[e] = 0.f; acc_s[e] = 0.f; }
        const unsigned short* Wg = Wcat + (size_t)(jg * 32 + lm) * 128 + h * 8;
        #pragma unroll
        for (int ks = 0; ks < 8; ++ks) {
            const short8 wi = *(const short8*)(const void*)(Wg + ks * 16);
            const short8 ws = *(const short8*)(const void*)(Wg + 256 * 128 + ks * 16);
            acc_i = mfma_bf16(wi, xf[ks], acc_i);
            acc_s = mfma_bf16(ws, xf[ks], acc_s);
        }
        #pragma unroll
        for (int q = 0; q < 4; ++q) {
            const int n0 = jg * 32 + q * 8 + h * 4;
            const float4 bi = *(const float4*)(Wi_b + n0);
            const float4 bs = *(const float4*)(Ws_b + n0);
            const float p0 = sigm(acc_i[q*4+0] + bi.x) * (acc_s[q*4+0] + bs.x);
            const float p1 = sigm(acc_i[q*4+1] + bi.y) * (acc_s[q*4+1] + bs.y);
            const float p2 = sigm(acc_i[q*4+2] + bi.z) * (acc_s[q*4+2] + bs.z);
            const float p3 = sigm(acc_i[q*4+3] + bi.w) * (acc_s[q*4+3] + bs.w);
            ppk[jg * 8 + q * 2 + 0] = pk_f16(p0, p1);
            ppk[jg * 8 + q * 2 + 1] = pk_f16(p2, p3);
        }
    }

    // ---------------- GEMM1 pass 2: f gate -> h_raw (bf16-packed) ------------
    unsigned hpk[32];                    // h_raw bf16 pairs, C layout
    #pragma unroll
    for (int jg = 0; jg < 4; ++jg) {
        f32x16 acc_f;
        #pragma unroll
        for (int e = 0; e < 16; ++e) acc_f[e] = 0.f;
        const unsigned short* Wg = Wcat + (size_t)(128 + jg * 32 + lm) * 128 + h * 8;
        #pragma unroll
        for (int ks = 0; ks < 8; ++ks) {
            const short8 wf = *(const short8*)(const void*)(Wg + ks * 16);
            acc_f = mfma_bf16(wf, xf[ks], acc_f);
        }
        #pragma unroll
        for (int q = 0; q < 4; ++q) {
            const int n0 = jg * 32 + q * 8 + h * 4;
            const float4 bf = *(const float4*)(fbias + n0);
            const float4 bh = *(const float4*)(hp + n0);
            const unsigned pa = ppk[jg * 8 + q * 2 + 0];
            const unsigned pb = ppk[jg * 8 + q * 2 + 1];
            const float h0 = lo_f16(pa) + sigm(acc_f[q*4+0] + bf.x) * bh.x;
            const float h1 = hi_f16(pa) + sigm(acc_f[q*4+1] + bf.y) * bh.y;
            const float h2 = lo_f16(pb) + sigm(acc_f[q*4+2] + bf.z) * bh.z;
            const float h3 = hi_f16(pb) + sigm(acc_f[q*4+3] + bf.w) * bh.w;
            hpk[jg * 8 + q * 2 + 0] = pk_bf16(h0, h1);
            hpk[jg * 8 + q * 2 + 1] = pk_bf16(h2, h3);
        }
    }

    // --- build GEMM2 B fragments once: bb = permlane-swapped copy of hpk -----
    unsigned bb[32];
    #pragma unroll
    for (int ks = 0; ks < 8; ++ks) {
        unsigned c0 = hpk[4*ks+0], c1 = hpk[4*ks+1], c2 = hpk[4*ks+2], c3 = hpk[4*ks+3];
        asm volatile("v_permlane32_swap_b32 %0, %1" : "+v"(c0), "+v"(c2));
        asm volatile("v_permlane32_swap_b32 %0, %1" : "+v"(c1), "+v"(c3));
        bb[4*ks+0] = c0; bb[4*ks+1] = c1; bb[4*ks+2] = c2; bb[4*ks+3] = c3;
    }

    // --- GEMM2 + per-T epilogue: o_t, h_out (f16-packed), LN partials --------
    unsigned opk[32];                    // h_out f16 pairs
    float sum = 0.f, ssq = 0.f;
    #pragma unroll
    for (int T = 0; T < 4; ++T) {
        f32x16 oacc;
        #pragma unroll
        for (int e = 0; e < 16; ++e) oacc[e] = 0.f;
        #pragma unroll
        for (int ks = 0; ks < 8; ++ks) {
            union { unsigned u[4]; short8 s8; } b4;
            b4.u[0] = bb[4*ks+0]; b4.u[1] = bb[4*ks+1];
            b4.u[2] = bb[4*ks+2]; b4.u[3] = bb[4*ks+3];
            const short8 wfrag = *(const short8*)(const void*)
                (Wo + (size_t)(T * 32 + lm) * 128 + ks * 16 + h * 8);
            oacc = mfma_bf16(wfrag, b4.s8, oacc);
        }
        #pragma unroll
        for (int q = 0; q < 4; ++q) {
            const int n0 = T * 32 + q * 8 + h * 4;
            const float4 bo = *(const float4*)(Wo_b + n0);
            const unsigned ha = hpk[T * 8 + q * 2 + 0];
            const unsigned hb = hpk[T * 8 + q * 2 + 1];
            const float hv0 = sigm(oacc[q*4+0] + bo.x) * tanh_fast(bf2f(ha & 0xffffu));
            const float hv1 = sigm(oacc[q*4+1] + bo.y) * tanh_fast(bf2f(ha >> 16));
            const float hv2 = sigm(oacc[q*4+2] + bo.z) * tanh_fast(bf2f(hb & 0xffffu));
            const float hv3 = sigm(oacc[q*4+3] + bo.w) * tanh_fast(bf2f(hb >> 16));
            opk[T * 8 + q * 2 + 0] = pk_f16(hv0, hv1);
            opk[T * 8 + q * 2 + 1] = pk_f16(hv2, hv3);
            sum += hv0 + hv1 + hv2 + hv3;
            ssq += hv0*hv0 + hv1*hv1 + hv2*hv2 + hv3*hv3;
        }
    }

    // --- LayerNorm over the 128 features of row m ----------------------------
    sum += __shfl_xor(sum, 32, 64);
    ssq += __shfl_xor(ssq, 32, 64);
    const float mean = sum * (1.0f / 128.0f);
    const float var  = ssq * (1.0f / 128.0f) - mean * mean;
    const float rstd = __builtin_amdgcn_rsqf(var + 1e-5f);

    float* orow = out + (size_t)m * 128;
    #pragma unroll
    for (int T = 0; T < 4; ++T) {
        #pragma unroll
        for (int q = 0; q < 4; ++q) {
            const int n0 = T * 32 + q * 8 + h * 4;
            const float4 g4 = *(const float4*)(ln_g + n0);
            const float4 b4 = *(const float4*)(ln_b + n0);
            const unsigned oa = opk[T * 8 + q * 2 + 0];
            const unsigned ob = opk[T * 8 + q * 2 + 1];
            float4 r;
            r.x = (lo_f16(oa) - mean) * rstd * g4.x + b4.x;
            r.y = (hi_f16(oa) - mean) * rstd * g4.y + b4.y;
            r.z = (lo_f16(ob) - mean) * rstd * g4.z + b4.z;
            r.w = (hi_f16(ob) - mean) * rstd * g4.w + b4.w;
            *(float4*)(orow + n0) = r;
        }
    }
}

// ------------------------------- launch ------------------------------------
extern "C" void kernel_launch(void* const* d_in, const int* in_sizes, int n_in,
                              void* d_out, int out_size, void* d_ws, size_t ws_size,
                              hipStream_t stream) {
    const float* x      = (const float*)d_in[0];
    const float* h_prev = (const float*)d_in[1];
    const float* Ws_w   = (const float*)d_in[2];
    const float* Ws_b   = (const float*)d_in[3];
    const float* Wfast  = (const float*)d_in[4];
    const float* Wi_w   = (const float*)d_in[5];
    const float* Wi_b   = (const float*)d_in[6];
    const float* Wf_w   = (const float*)d_in[7];
    const float* Wf_b   = (const float*)d_in[8];
    const float* Wo_w   = (const float*)d_in[9];
    const float* Wo_b   = (const float*)d_in[10];
    const float* ln_g   = (const float*)d_in[11];
    const float* ln_b   = (const float*)d_in[12];

    unsigned short* Wcat = (unsigned short*)d_ws;            // 384*128 bf16
    unsigned short* Wo   = Wcat + 384 * 128;                 // 128*128 bf16
    float*          fb   = (float*)(Wo + 128 * 128);         // 128 f32

    prep_weights<<<256, 256, 0, stream>>>(Wi_w, Wf_w, Ws_w, Wfast, Wo_w, Wcat, Wo);
    prep_fbias<<<1, 128, 0, stream>>>(Wf_w, Wf_b, h_prev, fb);

    const int B = in_sizes[0] / 128;                         // 262144
    const int blocks = B / 128;                              // 4 waves * 32 rows
    cell_main<<<blocks, 256, 0, stream>>>(x, h_prev, Wi_b, Ws_b, Wo_b,
                                          ln_g, ln_b, Wcat, Wo, fb,
                                          (float*)d_out);
}

// Round 4
// 190.852 us; speedup vs baseline: 1.1099x; 1.1099x over previous
//
#include <hip/hip_runtime.h>
#include <hip/hip_bf16.h>
#include <hip/hip_fp16.h>

// Fused AdvancedHomeostaticCell, round 4.
// R3 diagnosis: latency-bound on maximally-divergent vector loads (weights at
// 256-B lane stride, x at 512-B). Fix: (1) fragment-major pre-shuffled weight
// layout -> every weight load is one contiguous 1KB wave transaction;
// (2) x staged per-wave through XOR-swizzled LDS with coalesced global reads.
// Still zero barriers (each wave stages only its own 32 rows).

typedef __attribute__((ext_vector_type(8)))  short short8;
typedef __attribute__((ext_vector_type(16))) float f32x16;

__device__ __forceinline__ unsigned short f2bf(float f) {   // prep kernels only
    union { float f; unsigned u; } v; v.f = f;
    unsigned r = v.u + 0x7fffu + ((v.u >> 16) & 1u);
    return (unsigned short)(r >> 16);
}
__device__ __forceinline__ float bf2f(unsigned hs) {
    union { unsigned u; float f; } v; v.u = hs << 16;
    return v.f;
}
__device__ __forceinline__ unsigned pk_bf16(float lo, float hi) {
    union { __hip_bfloat162 h; unsigned u; } c;
    c.h = __float22bfloat162_rn(make_float2(lo, hi));
    return c.u;
}
__device__ __forceinline__ unsigned pk_f16(float lo, float hi) {
    union { __half2 h; unsigned u; } c;
    c.h = __floats2half2_rn(lo, hi);
    return c.u;
}
__device__ __forceinline__ float lo_f16(unsigned u) {
    union { unsigned u; __half2 h; } c; c.u = u;
    return __low2float(c.h);
}
__device__ __forceinline__ float hi_f16(unsigned u) {
    union { unsigned u; __half2 h; } c; c.u = u;
    return __high2float(c.h);
}
__device__ __forceinline__ float rcp_fast(float x) { return __builtin_amdgcn_rcpf(x); }
__device__ __forceinline__ float exp2_fast(float x) { return __builtin_amdgcn_exp2f(x); }
__device__ __forceinline__ float sigm(float x) {
    return rcp_fast(1.0f + exp2_fast(-1.4426950408889634f * x));
}
__device__ __forceinline__ float tanh_fast(float x) {
    return 1.0f - 2.0f * rcp_fast(1.0f + exp2_fast(2.8853900817779268f * x));
}
__device__ __forceinline__ f32x16 mfma_bf16(short8 a, short8 b, f32x16 c) {
    return __builtin_amdgcn_mfma_f32_32x32x16_bf16(a, b, c, 0, 0, 0);
}

// ---------- prep: fragment-major bf16 weights ------------------------------
// Wshuf element index = ((g*4 + jg)*8 + ks)*512 + lane*8 + e
//   g: 0=Wi, 1=Wf(x half), 2=Wslow+Wfast, 3=Wo ; jg: n-tile ; ks: k-tile
//   fragment value[e] = Wg[jg*32 + (lane&31)][ks*16 + (lane>>5)*8 + e]
__global__ void prep_weights(const float* __restrict__ Wi_w,
                             const float* __restrict__ Wf_w,
                             const float* __restrict__ Ws_w,
                             const float* __restrict__ Wfast_w,
                             const float* __restrict__ Wo_w,
                             unsigned short* __restrict__ Wshuf) {
    int gid = blockIdx.x * 256 + threadIdx.x;   // 0 .. 65535
    int e    = gid & 7;
    int lane = (gid >> 3) & 63;
    int ks   = (gid >> 9) & 7;
    int t    = gid >> 12;                       // g*4 + jg
    int g = t >> 2, jg = t & 3;
    int row = jg * 32 + (lane & 31);
    int k   = ks * 16 + (lane >> 5) * 8 + e;
    float v;
    if (g == 0)      v = Wi_w[row * 128 + k];
    else if (g == 1) v = Wf_w[row * 256 + k];
    else if (g == 2) v = Ws_w[row * 128 + k] + Wfast_w[row * 128 + k];
    else             v = Wo_w[row * 128 + k];
    Wshuf[gid] = f2bf(v);
}

// fbias[j] = Wf_b[j] + sum_k Wf_w[j][128+k] * h_prev[k]
__global__ void prep_fbias(const float* __restrict__ Wf_w,
                           const float* __restrict__ Wf_b,
                           const float* __restrict__ hp,
                           float* __restrict__ fbias) {
    int j = threadIdx.x;
    float s = Wf_b[j];
    for (int k = 0; k < 128; ++k) s += Wf_w[j * 256 + 128 + k] * hp[k];
    fbias[j] = s;
}

// ------------------------------ main fused kernel --------------------------
__global__ __launch_bounds__(256, 3)
void cell_main(const float* __restrict__ x,
               const float* __restrict__ hp,
               const float* __restrict__ Wi_b,
               const float* __restrict__ Ws_b,
               const float* __restrict__ Wo_b,
               const float* __restrict__ ln_g,
               const float* __restrict__ ln_b,
               const unsigned short* __restrict__ Wshuf,
               const float* __restrict__ fbias,
               float* __restrict__ out) {
    const int tid  = threadIdx.x;
    const int lane = tid & 63;
    const int warp = tid >> 6;
    const int lm   = lane & 31;          // column m within wave tile / weight row
    const int h    = lane >> 5;          // half-wave selector (k-block)
    const int wave_id = blockIdx.x * 4 + warp;

    __shared__ __align__(16) char smem[32768];   // 4 waves x 8KB (32 rows bf16)
    char* myLds = smem + warp * 8192;

    // --- stage this wave's 32 x-rows: coalesced f32 reads -> swizzled LDS ---
    {
        const float* xbase = x + (size_t)wave_id * 32 * 128;
        #pragma unroll
        for (int it = 0; it < 16; ++it) {
            const float4 v = *(const float4*)(xbase + (size_t)(it * 64 + lane) * 4);
            const int r = it * 2 + h;                 // local row 0..31
            unsigned byteoff = (unsigned)(r * 256 + lm * 8);
            byteoff ^= (unsigned)((r & 15) << 4);
            *(uint2*)(myLds + byteoff) = make_uint2(pk_bf16(v.x, v.y), pk_bf16(v.z, v.w));
        }
    }

    // --- read xf fragments back: k = 16*ks + 8*h + 0..7 of own row lm --------
    short8 xf[8];
    #pragma unroll
    for (int ks = 0; ks < 8; ++ks) {
        unsigned byteoff = (unsigned)(lm * 256 + ks * 32 + h * 16);
        byteoff ^= (unsigned)((lm & 15) << 4);
        xf[ks] = *(const short8*)(myLds + byteoff);
    }

    // coalesced fragment-major weight loads: 1KB contiguous per wave instr
    const unsigned short* Wl = Wshuf + (size_t)lane * 8;
    #define WFRAG(g, jg, ks) (*(const short8*)(const void*)(Wl + (size_t)(((g)*4 + (jg))*8 + (ks)) * 512))

    // ---------------- GEMM1 pass 1: i and s gates -> part = sigm(i)*(s+b) ----
    // acc layout (32x32x16): col = lane&31 (=m), row = (r&3)+8*(r>>2)+4*h
    unsigned ppk[32];                    // part packed f16 pairs
    #pragma unroll
    for (int jg = 0; jg < 4; ++jg) {
        f32x16 acc_i, acc_s;
        #pragma unroll
        for (int e = 0; e < 16; ++e) { acc_i[e] = 0.f; acc_s[e] = 0.f; }
        #pragma unroll
        for (int ks = 0; ks < 8; ++ks) {
            acc_i = mfma_bf16(WFRAG(0, jg, ks), xf[ks], acc_i);
            acc_s = mfma_bf16(WFRAG(2, jg, ks), xf[ks], acc_s);
        }
        #pragma unroll
        for (int q = 0; q < 4; ++q) {
            const int n0 = jg * 32 + q * 8 + h * 4;
            const float4 bi = *(const float4*)(Wi_b + n0);
            const float4 bs = *(const float4*)(Ws_b + n0);
            const float p0 = sigm(acc_i[q*4+0] + bi.x) * (acc_s[q*4+0] + bs.x);
            const float p1 = sigm(acc_i[q*4+1] + bi.y) * (acc_s[q*4+1] + bs.y);
            const float p2 = sigm(acc_i[q*4+2] + bi.z) * (acc_s[q*4+2] + bs.z);
            const float p3 = sigm(acc_i[q*4+3] + bi.w) * (acc_s[q*4+3] + bs.w);
            ppk[jg * 8 + q * 2 + 0] = pk_f16(p0, p1);
            ppk[jg * 8 + q * 2 + 1] = pk_f16(p2, p3);
        }
    }

    // ---------------- GEMM1 pass 2: f gate -> h_raw (bf16-packed) ------------
    unsigned hpk[32];                    // h_raw bf16 pairs, C layout
    #pragma unroll
    for (int jg = 0; jg < 4; ++jg) {
        f32x16 acc_f;
        #pragma unroll
        for (int e = 0; e < 16; ++e) acc_f[e] = 0.f;
        #pragma unroll
        for (int ks = 0; ks < 8; ++ks)
            acc_f = mfma_bf16(WFRAG(1, jg, ks), xf[ks], acc_f);
        #pragma unroll
        for (int q = 0; q < 4; ++q) {
            const int n0 = jg * 32 + q * 8 + h * 4;
            const float4 bf = *(const float4*)(fbias + n0);
            const float4 bh = *(const float4*)(hp + n0);
            const unsigned pa = ppk[jg * 8 + q * 2 + 0];
            const unsigned pb = ppk[jg * 8 + q * 2 + 1];
            const float h0 = lo_f16(pa) + sigm(acc_f[q*4+0] + bf.x) * bh.x;
            const float h1 = hi_f16(pa) + sigm(acc_f[q*4+1] + bf.y) * bh.y;
            const float h2 = lo_f16(pb) + sigm(acc_f[q*4+2] + bf.z) * bh.z;
            const float h3 = hi_f16(pb) + sigm(acc_f[q*4+3] + bf.w) * bh.w;
            hpk[jg * 8 + q * 2 + 0] = pk_bf16(h0, h1);
            hpk[jg * 8 + q * 2 + 1] = pk_bf16(h2, h3);
        }
    }

    // --- build GEMM2 B fragments once: bb = permlane-swapped copy of hpk -----
    unsigned bb[32];
    #pragma unroll
    for (int ks = 0; ks < 8; ++ks) {
        unsigned c0 = hpk[4*ks+0], c1 = hpk[4*ks+1], c2 = hpk[4*ks+2], c3 = hpk[4*ks+3];
        asm volatile("v_permlane32_swap_b32 %0, %1" : "+v"(c0), "+v"(c2));
        asm volatile("v_permlane32_swap_b32 %0, %1" : "+v"(c1), "+v"(c3));
        bb[4*ks+0] = c0; bb[4*ks+1] = c1; bb[4*ks+2] = c2; bb[4*ks+3] = c3;
    }

    // --- GEMM2 + per-T epilogue: o_t, h_out (f16-packed), LN partials --------
    unsigned opk[32];                    // h_out f16 pairs
    float sum = 0.f, ssq = 0.f;
    #pragma unroll
    for (int T = 0; T < 4; ++T) {
        f32x16 oacc;
        #pragma unroll
        for (int e = 0; e < 16; ++e) oacc[e] = 0.f;
        #pragma unroll
        for (int ks = 0; ks < 8; ++ks) {
            union { unsigned u[4]; short8 s8; } b4;
            b4.u[0] = bb[4*ks+0]; b4.u[1] = bb[4*ks+1];
            b4.u[2] = bb[4*ks+2]; b4.u[3] = bb[4*ks+3];
            oacc = mfma_bf16(WFRAG(3, T, ks), b4.s8, oacc);
        }
        #pragma unroll
        for (int q = 0; q < 4; ++q) {
            const int n0 = T * 32 + q * 8 + h * 4;
            const float4 bo = *(const float4*)(Wo_b + n0);
            const unsigned ha = hpk[T * 8 + q * 2 + 0];
            const unsigned hb = hpk[T * 8 + q * 2 + 1];
            const float hv0 = sigm(oacc[q*4+0] + bo.x) * tanh_fast(bf2f(ha & 0xffffu));
            const float hv1 = sigm(oacc[q*4+1] + bo.y) * tanh_fast(bf2f(ha >> 16));
            const float hv2 = sigm(oacc[q*4+2] + bo.z) * tanh_fast(bf2f(hb & 0xffffu));
            const float hv3 = sigm(oacc[q*4+3] + bo.w) * tanh_fast(bf2f(hb >> 16));
            opk[T * 8 + q * 2 + 0] = pk_f16(hv0, hv1);
            opk[T * 8 + q * 2 + 1] = pk_f16(hv2, hv3);
            sum += hv0 + hv1 + hv2 + hv3;
            ssq += hv0*hv0 + hv1*hv1 + hv2*hv2 + hv3*hv3;
        }
    }

    // --- LayerNorm over the 128 features of row m ----------------------------
    sum += __shfl_xor(sum, 32, 64);
    ssq += __shfl_xor(ssq, 32, 64);
    const float mean = sum * (1.0f / 128.0f);
    const float var  = ssq * (1.0f / 128.0f) - mean * mean;
    const float rstd = __builtin_amdgcn_rsqf(var + 1e-5f);

    const int m = wave_id * 32 + lm;
    float* orow = out + (size_t)m * 128;
    #pragma unroll
    for (int T = 0; T < 4; ++T) {
        #pragma unroll
        for (int q = 0; q < 4; ++q) {
            const int n0 = T * 32 + q * 8 + h * 4;
            const float4 g4 = *(const float4*)(ln_g + n0);
            const float4 b4 = *(const float4*)(ln_b + n0);
            const unsigned oa = opk[T * 8 + q * 2 + 0];
            const unsigned ob = opk[T * 8 + q * 2 + 1];
            float4 r;
            r.x = (lo_f16(oa) - mean) * rstd * g4.x + b4.x;
            r.y = (hi_f16(oa) - mean) * rstd * g4.y + b4.y;
            r.z = (lo_f16(ob) - mean) * rstd * g4.z + b4.z;
            r.w = (hi_f16(ob) - mean) * rstd * g4.w + b4.w;
            *(float4*)(orow + n0) = r;
        }
    }
    #undef WFRAG
}

// ------------------------------- launch ------------------------------------
extern "C" void kernel_launch(void* const* d_in, const int* in_sizes, int n_in,
                              void* d_out, int out_size, void* d_ws, size_t ws_size,
                              hipStream_t stream) {
    const float* x      = (const float*)d_in[0];
    const float* h_prev = (const float*)d_in[1];
    const float* Ws_w   = (const float*)d_in[2];
    const float* Ws_b   = (const float*)d_in[3];
    const float* Wfast  = (const float*)d_in[4];
    const float* Wi_w   = (const float*)d_in[5];
    const float* Wi_b   = (const float*)d_in[6];
    const float* Wf_w   = (const float*)d_in[7];
    const float* Wf_b   = (const float*)d_in[8];
    const float* Wo_w   = (const float*)d_in[9];
    const float* Wo_b   = (const float*)d_in[10];
    const float* ln_g   = (const float*)d_in[11];
    const float* ln_b   = (const float*)d_in[12];

    unsigned short* Wshuf = (unsigned short*)d_ws;           // 65536 bf16 = 128 KB
    float*          fb    = (float*)(Wshuf + 65536);         // 128 f32

    prep_weights<<<256, 256, 0, stream>>>(Wi_w, Wf_w, Ws_w, Wfast, Wo_w, Wshuf);
    prep_fbias<<<1, 128, 0, stream>>>(Wf_w, Wf_b, h_prev, fb);

    const int B = in_sizes[0] / 128;                         // 262144
    const int blocks = B / 128;                              // 4 waves * 32 rows
    cell_main<<<blocks, 256, 0, stream>>>(x, h_prev, Wi_b, Ws_b, Wo_b,
                                          ln_g, ln_b, Wshuf, fb,
                                          (float*)d_out);
}